// Round 1
// 181.345 us; speedup vs baseline: 1.0763x; 1.0763x over previous
//
#include <hip/hip_runtime.h>
#include <cstdint>
#include <cstddef>

// Problem constants
#define CIN_K  512
#define WW_    38
#define BHW    1444          // 38*38
#define NOUT   255
#define MTOT   46208         // 32*1444 == 722*64

#define KCH    256           // K elems staged per chunk (2 chunks of 256)
#define ROW_E  260           // bf16 elems per As row: 256 + 4 pad (130 dw, 130%32==2)
#define EP_DW  260           // fp32 dwords per epilogue row (32 rows x 260 dw = 33,280 B)

typedef __attribute__((ext_vector_type(8))) short  bf16x8;
typedef __attribute__((ext_vector_type(4))) float  floatx4;

static __device__ __forceinline__ unsigned f2bf(float f) {
    unsigned u = __builtin_bit_cast(unsigned, f);
    return (u + 0x7FFFu + ((u >> 16) & 1u)) >> 16;   // RNE to bf16
}

// ---- pass 1: cw fp32 [255][512] -> wb bf16 [256][512], row 255 zeroed ----
__global__ void conv_w_to_bf16(const float* __restrict__ cw,
                               unsigned short* __restrict__ wb) {
    int tg   = blockIdx.x * 256 + threadIdx.x;   // 0..16383
    int base = tg * 8;
    int n    = base >> 9;
    unsigned rr[4] = {0u, 0u, 0u, 0u};
    if (n < NOUT) {
        float4 v0 = *(const float4*)(cw + base);
        float4 v1 = *(const float4*)(cw + base + 4);
        rr[0] = f2bf(v0.x) | (f2bf(v0.y) << 16);
        rr[1] = f2bf(v0.z) | (f2bf(v0.w) << 16);
        rr[2] = f2bf(v1.x) | (f2bf(v1.y) << 16);
        rr[3] = f2bf(v1.z) | (f2bf(v1.w) << 16);
    }
    *(uint4*)(wb + base) = *(uint4*)rr;
}

// ---- pass 2: K-chunked GEMM + fused YOLO decode ----
// Block: 64 m-rows x 256 n. Wave w: n-slice [w*64, w*64+64), all 64 m.
// A staged in LDS in 2 K-chunks of 256 (33,280 B -> 4 blocks/CU).
// Staging: float4 along m (16B/lane) + in-register 4x4 transpose -> b64 LDS writes.
__global__ __launch_bounds__(256, 4)
void yolo_head(const float* __restrict__ xin,          // [32,512,38,38] fp32
               const unsigned short* __restrict__ wb,  // [256,512] bf16
               const float* __restrict__ cb,           // [255] fp32
               float* __restrict__ out)                // [46208,255] fp32
{
    __shared__ unsigned smem[64 * (ROW_E / 2)];        // 64*130 dw = 33,280 B
    unsigned short* As = (unsigned short*)smem;

    const int t    = threadIdx.x;
    const int w    = t >> 6;       // wave id -> n-slice w*64
    const int lane = t & 63;
    const int l15  = lane & 15;
    const int q    = lane >> 4;
    const int m0   = blockIdx.x * 64;

    // staging coords: thread owns a 4m x 4k micro-tile per iteration
    const int mq4 = (t & 15) * 4;          // m-quad base within block (0..60)
    const int kq4 = (t >> 4) * 4;          // k-quad base within 64-k slab (0..60)
    const int m4  = m0 + mq4;
    const int bi  = m4 / BHW;              // m-quad never straddles b (BHW%4==0, m4%4==0)
    const int hw  = m4 - bi * BHW;
    const float* pb0 = xin + (size_t)bi * (CIN_K * BHW) + hw;

    floatx4 acc[4][4];
#pragma unroll
    for (int i = 0; i < 4; ++i)
#pragma unroll
        for (int j = 0; j < 4; ++j)
            acc[i][j] = (floatx4){0.f, 0.f, 0.f, 0.f};

    // B frag addr: n = w*64 + j*16 + l15, k = ck*256 + kc*32 + q*8
    const unsigned short* pbw = wb + (size_t)(w * 64 + l15) * CIN_K + q * 8;

#pragma unroll
    for (int ck = 0; ck < 2; ++ck) {
        if (ck) __syncthreads();           // all readers of previous chunk done

        // -------- stage chunk ck: 64 m x 256 k fp32 -> bf16 in LDS ----------
#pragma unroll
        for (int it = 0; it < 4; ++it) {   // 4 slabs of 64 k
            const int kl = it * 64 + kq4;  // k local to chunk (0..252, mult of 4)
            alignas(16) float vv[4][4];
#pragma unroll
            for (int kk = 0; kk < 4; ++kk)
                *(float4*)&vv[kk][0] =
                    *(const float4*)(pb0 + (size_t)(ck * KCH + kl + kk) * BHW);
            // in-register 4x4 transpose: pack 4 k for each of 4 m
#pragma unroll
            for (int r = 0; r < 4; ++r) {
                unsigned lo = f2bf(vv[0][r]) | (f2bf(vv[1][r]) << 16);
                unsigned hi = f2bf(vv[2][r]) | (f2bf(vv[3][r]) << 16);
                uint2 pk = make_uint2(lo, hi);
                *(uint2*)(&As[(mq4 + r) * ROW_E + kl]) = pk;   // b64, conflict-free
            }
        }
        __syncthreads();

        // -------- compute 8 K-steps on this chunk ---------------------------
#pragma unroll
        for (int kc = 0; kc < 8; ++kc) {
            bf16x8 bfr[4], af[4];
#pragma unroll
            for (int j = 0; j < 4; ++j) {
                uint4 bv = *(const uint4*)(pbw + (size_t)j * 16 * CIN_K
                                           + ck * KCH + kc * 32);
                bfr[j] = __builtin_bit_cast(bf16x8, bv);
            }
#pragma unroll
            for (int i = 0; i < 4; ++i) {
                int4 av = *(const int4*)(&As[(i * 16 + l15) * ROW_E + kc * 32 + q * 8]);
                af[i] = __builtin_bit_cast(bf16x8, av);
            }
#pragma unroll
            for (int i = 0; i < 4; ++i)
#pragma unroll
                for (int j = 0; j < 4; ++j)
                    acc[i][j] = __builtin_amdgcn_mfma_f32_16x16x32_bf16(
                                    af[i], bfr[j], acc[i][j], 0, 0, 0);
        }
    }

    // -------- fused YOLO decode (in place on acc) --------------------------
    // C/D layout: col(n) = l15 (+16j), row(m) = i*16 + q*4 + r
#pragma unroll
    for (int j = 0; j < 4; ++j) {
        int   n    = w * 64 + j * 16 + l15;
        int   nc   = n < NOUT ? n : NOUT - 1;
        int   ai   = nc / 85;
        int   ji   = nc - ai * 85;
        float bias = cb[nc];
        float aw   = (ai == 0) ? 30.f : (ai == 1) ? 62.f : 59.f;
        float ah   = (ai == 0) ? 61.f : (ai == 1) ? 45.f : 119.f;
#pragma unroll
        for (int i = 0; i < 4; ++i)
#pragma unroll
            for (int r = 0; r < 4; ++r) {
                int   md  = m0 + i * 16 + q * 4 + r;
                int   rem = md % BHW;
                int   hh  = rem / WW_;
                float v   = acc[i][j][r] + bias;
                float res;
                if (ji == 0)      res = (1.f / (1.f + __expf(-v)) + (float)(rem - hh * WW_)) * 16.f;
                else if (ji == 1) res = (1.f / (1.f + __expf(-v)) + (float)hh) * 16.f;
                else if (ji == 2) res = __expf(v) * aw;
                else if (ji == 3) res = __expf(v) * ah;
                else              res = v;
                acc[i][j][r] = res;
            }
    }

    // -------- epilogue: LDS transpose + aligned stores, 2 passes of 32 rows -
    float* EP = (float*)smem;
#pragma unroll
    for (int p = 0; p < 2; ++p) {
        __syncthreads();                   // previous LDS readers done
#pragma unroll
        for (int i2 = 0; i2 < 2; ++i2) {
            const int i = p * 2 + i2;
#pragma unroll
            for (int j = 0; j < 4; ++j)
#pragma unroll
                for (int r = 0; r < 4; ++r)
                    EP[(i2 * 16 + q * 4 + r) * EP_DW + w * 64 + j * 16 + l15] =
                        acc[i][j][r];
        }
        __syncthreads();

        // wave w stores rows [p*32 + w*8, +8): 8*255 = 2040 floats, 16B-aligned
        const float* EPb = (const float*)smem + (w * 8) * EP_DW;
        float*       ob  = out + (size_t)(m0 + p * 32 + w * 8) * NOUT;
#pragma unroll
        for (int s2 = 0; s2 < 8; ++s2) {
            int f4 = s2 * 64 + lane;       // float4 index, 0..509
            if (f4 < 510) {
                int   f = f4 * 4;
                float vs[4];
#pragma unroll
                for (int e = 0; e < 4; ++e) {
                    int fe = f + e;
                    int mr = fe / NOUT;
                    int x  = fe - mr * NOUT;
                    vs[e]  = EPb[mr * EP_DW + x];
                }
                *(float4*)(ob + f) = make_float4(vs[0], vs[1], vs[2], vs[3]);
            }
        }
    }
}

extern "C" void kernel_launch(void* const* d_in, const int* in_sizes, int n_in,
                              void* d_out, int out_size, void* d_ws, size_t ws_size,
                              hipStream_t stream) {
    const float* xin = (const float*)d_in[0];
    const float* cw  = (const float*)d_in[1];
    const float* cb  = (const float*)d_in[2];
    float*       out = (float*)d_out;
    unsigned short* wb = (unsigned short*)d_ws;   // 256*512*2 = 256 KiB

    hipLaunchKernelGGL(conv_w_to_bf16, dim3(64), dim3(256), 0, stream, cw, wb);
    hipLaunchKernelGGL(yolo_head, dim3(MTOT / 64), dim3(256), 0, stream,
                       xin, wb, cb, out);
}